// Round 6
// baseline (906.958 us; speedup 1.0000x reference)
//
#include <hip/hip_runtime.h>
#include <math.h>

#define B_N 256
#define T_N 1024
#define D_N 128
#define H_N 256
#define NSEG 16    // t-segments per b; each block covers 64 t

// LDS (shorts): sP/sQ ping-pong activations (64 rows x SPS each), 8-short
// guard (zeroed; catches last-row K-overrun b128 reads), accum floats.
// NOTE: single-buffer same-region variant triggered 25MB scratch (R4) — keep
// the ping-pong.
#define SPS 120                   // 112 cols + pad; 16B-unit stride 15 (odd) -> conflict-free
#define SP_OFF  0                 // 64*120 = 7680
#define SQ_OFF  7680              // 7680
#define GUARD_OFF 15360           // 8 zeroed shorts
#define ACC_OFF 15368             // 512 shorts = 256 floats (byte 30736, 16B-mult)
#define SMEM_SH 15880             // 31,760 B

typedef __attribute__((ext_vector_type(8))) short short8;   // 8 bf16 = 4 VGPRs
typedef __attribute__((ext_vector_type(4))) float f32x4;

// ws layout (bf16 units): weights in MFMA fragment order; each B-fragment is
// ONE coalesced 1KB global_load_dwordx4 (lane i reads bytes [16i,16i+16)).
//   elem index within layer: ((nt*KR + k4)*64 + lane)*8 + j = (nt*KR+k4)*512 + lane*8 + j
//   holds WT[n = nt*16 + (lane&15)][k = k4*32 + (lane>>4)*8 + j], zero-padded.
#define WXT_OFF 0         // NT=16 KR=4 -> 32768
#define W1T_OFF 32768     // NT=7  KR=4 -> 14336
#define W2T_OFF 47104     // NT=7  KR=4 -> 14336   rows k>=100 ZERO
#define W3T_OFF 61440     // NT=7  KR=4 -> 14336
#define W4T_OFF 75776     // NT=4  KR=4 ->  8192
#define W5T_OFF 83968     // NT=16 KR=2 -> 16384   rows k>=50 zero
#define WT_TOTAL 100352
// done-counters: 256 ints right after the weights in ws (byte off 200,704)

__device__ __forceinline__ float sigmoid_f(float z) {
    return 1.0f / (1.0f + __expf(-z));
}
__device__ __forceinline__ unsigned short f2bf(float f) {   // RNE fp32->bf16
    unsigned u = __float_as_uint(f);
    return (unsigned short)((u + 0x7FFFu + ((u >> 16) & 1u)) >> 16);
}

// ---- prep: fp32 W[K][N] -> bf16 fragment-ordered + zero out[] and cnt[]
__global__ __launch_bounds__(256) void prep_init(
    const float* __restrict__ Wx, const float* __restrict__ W1,
    const float* __restrict__ W2, const float* __restrict__ W3,
    const float* __restrict__ W4, const float* __restrict__ W5,
    short* __restrict__ wt, float* __restrict__ out, int* __restrict__ cnt)
{
    int idx = blockIdx.x * 256 + threadIdx.x;
    // zero out (65792 floats = 16448 float4) + cnt (256 ints)
    if (idx < 16448) {
        const float4 z = {0.f, 0.f, 0.f, 0.f};
        reinterpret_cast<float4*>(out)[idx] = z;
    } else if (idx < 16448 + 256) {
        cnt[idx - 16448] = 0;
    }
    if (idx >= WT_TOTAL) return;
    const float* src; int base, KR, K, N;
    if (idx < W1T_OFF)      { src = Wx; base = WXT_OFF; KR = 4; K = 128; N = 256; }
    else if (idx < W2T_OFF) { src = W1; base = W1T_OFF; KR = 4; K = 128; N = 100; }
    else if (idx < W3T_OFF) { src = W2; base = W2T_OFF; KR = 4; K = 100; N = 100; }
    else if (idx < W4T_OFF) { src = W3; base = W3T_OFF; KR = 4; K = 100; N = 100; }
    else if (idx < W5T_OFF) { src = W4; base = W4T_OFF; KR = 4; K = 100; N =  50; }
    else                    { src = W5; base = W5T_OFF; KR = 2; K =  50; N = 256; }
    int e    = idx - base;
    int j    = e & 7;
    int slot = e >> 3;            // (nt*KR + k4)*64 + lane
    int lane = slot & 63;
    int kk   = slot >> 6;
    int k4   = kk & (KR - 1);
    int nt   = kk / KR;
    int n = nt * 16 + (lane & 15);
    int k = k4 * 32 + (lane >> 4) * 8 + j;
    float v = (k < K && n < N) ? src[(size_t)k * N + n] : 0.0f;
    wt[idx] = (short)f2bf(v);
}

// A-fragment set (K=128): lane holds A[m=lr][k = k*32 + lq*8 + j]
__device__ __forceinline__ void loadA(const short* __restrict__ base, short8 (&a)[4],
                                      int mbase, int lr, int lq)
{
    #pragma unroll
    for (int k = 0; k < 4; ++k)
        a[k] = *reinterpret_cast<const short8*>(&base[(mbase + lr) * SPS + k * 32 + lq * 8]);
}

// Software-pipelined dense layer: EXPLICIT 2-deep B prefetch (named cur/next
// fragment regs force the allocator past its 64-VGPR occupancy heuristic —
// R1/R2/R5 all pinned VGPR=64 leaving exactly ONE tile in flight; every tile
// paid full L2 latency serially). Split-K accumulators (e/o) halve the MFMA
// dependent chain. Fully unrolled: all array indices static (no scratch).
template<int NT>
__device__ __forceinline__ void denseLP(const short8 (&a)[4], const short* __restrict__ gW,
                                        const float* __restrict__ bias, int ncap,
                                        short* __restrict__ dst, int mbase, int lr, int lq,
                                        int lane)
{
    const short* gp = gW + lane * 8;
    short8 bc[4], bn[4];
    #pragma unroll
    for (int k = 0; k < 4; ++k)
        bc[k] = *reinterpret_cast<const short8*>(gp + k * 512);
    #pragma unroll
    for (int nt = 0; nt < NT; ++nt) {
        if (nt + 1 < NT) {             // issue NEXT tile's loads before this tile's MFMAs
            #pragma unroll
            for (int k = 0; k < 4; ++k)
                bn[k] = *reinterpret_cast<const short8*>(gp + ((nt + 1) * 4 + k) * 512);
        }
        f32x4 e = {0.f, 0.f, 0.f, 0.f}, o = {0.f, 0.f, 0.f, 0.f};
        e = __builtin_amdgcn_mfma_f32_16x16x32_bf16(a[0], bc[0], e, 0, 0, 0);
        o = __builtin_amdgcn_mfma_f32_16x16x32_bf16(a[1], bc[1], o, 0, 0, 0);
        e = __builtin_amdgcn_mfma_f32_16x16x32_bf16(a[2], bc[2], e, 0, 0, 0);
        o = __builtin_amdgcn_mfma_f32_16x16x32_bf16(a[3], bc[3], o, 0, 0, 0);
        const int n0 = nt * 16;
        const bool valid = (n0 + lr < ncap);
        const float bv = valid ? bias[n0 + lr] : 0.0f;
        #pragma unroll
        for (int r = 0; r < 4; ++r) {
            float v = valid ? fmaxf(e[r] + o[r] + bv, 0.0f) : 0.0f;
            dst[(mbase + lq * 4 + r) * SPS + n0 + lr] = (short)f2bf(v);
        }
        if (nt + 1 < NT) {
            #pragma unroll
            for (int k = 0; k < 4; ++k) bc[k] = bn[k];   // renamed away by unroll
        }
    }
}

// Fused MLP + linearized scan + (last block per b) the output head.
//   hidden[b,h] = sum_t gate[t,b,(h - s*(T-1-t)) mod H]
// Grid 4096 = 16 t-segments x 256 batch; block = 4 waves x 16 t-rows each.
// launch_bounds(256,3): budget ~170 VGPR; explicit prefetch dataflow needs
// ~100 -> allocator must leave the 64-reg class (watch VGPR_Count as the
// signature). 3 waves/EU floor = 12 waves/CU ~= current measured residency.
__global__ __launch_bounds__(256, 3) void srnn_gate_scan(
    const float* __restrict__ x, const short* __restrict__ wt,
    const float* __restrict__ bx, const float* __restrict__ b1,
    const float* __restrict__ b2, const float* __restrict__ b3,
    const float* __restrict__ b4, const float* __restrict__ b5,
    const int* __restrict__ shiftp,
    const float* __restrict__ Wo, const float* __restrict__ bo,
    int* __restrict__ cnt,
    float* __restrict__ out)   // out[0..255]=output, out[256..]=hidden
{
    __shared__ __align__(16) short smem[SMEM_SH];
    short* sP = smem + SP_OFF;
    short* sQ = smem + SQ_OFF;
    float* accum = reinterpret_cast<float*>(smem + ACC_OFF);

    const int tid  = threadIdx.x;
    const int b    = blockIdx.x & 255;
    const int seg  = blockIdx.x >> 8;      // 0..15
    const int lane = tid & 63;
    const int mbase = (tid >> 6) * 16;     // wave's row base in LDS
    const int lr = lane & 15;              // A m-index / B n-index / C-D col
    const int lq = lane >> 4;              // quad; C/D row = lq*4+r
    const int s  = *shiftp;
    const int tw0 = seg * 64 + mbase;      // t of this wave's row 0

    // zero ALL of LDS (act pads + guard finite; accum zeroed for atomics)
    {
        const float4 z = {0.f, 0.f, 0.f, 0.f};
        float4* dst = reinterpret_cast<float4*>(smem);
        #pragma unroll
        for (int i = 0; i < 8; ++i) {
            int sl = tid + i * 256;
            if (sl < SMEM_SH / 8) dst[sl] = z;
        }
    }

    // x A-fragments straight from global (row = lr per lane), f2bf in regs
    short8 ax4[4];
    {
        const float* xr = x + ((size_t)b * T_N + tw0 + lr) * D_N;
        #pragma unroll
        for (int k = 0; k < 4; ++k) {
            const float4 v0 = *reinterpret_cast<const float4*>(&xr[k * 32 + lq * 8]);
            const float4 v1 = *reinterpret_cast<const float4*>(&xr[k * 32 + lq * 8 + 4]);
            short8 t;
            t[0] = (short)f2bf(v0.x); t[1] = (short)f2bf(v0.y);
            t[2] = (short)f2bf(v0.z); t[3] = (short)f2bf(v0.w);
            t[4] = (short)f2bf(v1.x); t[5] = (short)f2bf(v1.y);
            t[6] = (short)f2bf(v1.z); t[7] = (short)f2bf(v1.w);
            ax4[k] = t;
        }
    }
    __syncthreads();                       // zero-init visible to all waves

    // ---- MLP chain, zero barriers (wave-private rows; sP/sQ ping-pong)
    short8 aL[4];
    denseLP<7>(ax4, wt + W1T_OFF, b1, 100, sP, mbase, lr, lq, lane);
    loadA(sP, aL, mbase, lr, lq);
    denseLP<7>(aL, wt + W2T_OFF, b2, 100, sQ, mbase, lr, lq, lane);
    loadA(sQ, aL, mbase, lr, lq);
    denseLP<7>(aL, wt + W3T_OFF, b3, 100, sP, mbase, lr, lq, lane);
    loadA(sP, aL, mbase, lr, lq);
    denseLP<4>(aL, wt + W4T_OFF, b4, 50, sQ, mbase, lr, lq, lane);

    // L4 output as K=64 A-fragments for L5 (cols 50..63 zero from ncap)
    short8 c0 = *reinterpret_cast<const short8*>(&sQ[(mbase + lr) * SPS + 0 + lq * 8]);
    short8 c1 = *reinterpret_cast<const short8*>(&sQ[(mbase + lr) * SPS + 32 + lq * 8]);

    // ---- tail: Lx (A=ax4) + L5 (A=c0/c1) + gate + scatter, 16 n-tiles,
    // software-pipelined the same way (explicit next-tile Wx AND W5 prefetch)
    const short* gpx = wt + WXT_OFF + lane * 8;
    const short* gp5 = wt + W5T_OFF + lane * 8;
    const int tbase = T_N - 1 - tw0;
    short8 wc[4], wn[4], vc[2], vn[2];
    #pragma unroll
    for (int k = 0; k < 4; ++k)
        wc[k] = *reinterpret_cast<const short8*>(gpx + k * 512);
    vc[0] = *reinterpret_cast<const short8*>(gp5 + 0 * 512);
    vc[1] = *reinterpret_cast<const short8*>(gp5 + 1 * 512);
    #pragma unroll
    for (int ntl = 0; ntl < 16; ++ntl) {
        if (ntl + 1 < 16) {
            #pragma unroll
            for (int k = 0; k < 4; ++k)
                wn[k] = *reinterpret_cast<const short8*>(gpx + ((ntl + 1) * 4 + k) * 512);
            vn[0] = *reinterpret_cast<const short8*>(gp5 + ((ntl + 1) * 2 + 0) * 512);
            vn[1] = *reinterpret_cast<const short8*>(gp5 + ((ntl + 1) * 2 + 1) * 512);
        }
        const int n0 = ntl * 16;
        f32x4 e = {0.f, 0.f, 0.f, 0.f}, o = {0.f, 0.f, 0.f, 0.f};
        e = __builtin_amdgcn_mfma_f32_16x16x32_bf16(ax4[0], wc[0], e, 0, 0, 0);
        o = __builtin_amdgcn_mfma_f32_16x16x32_bf16(ax4[1], wc[1], o, 0, 0, 0);
        e = __builtin_amdgcn_mfma_f32_16x16x32_bf16(ax4[2], wc[2], e, 0, 0, 0);
        o = __builtin_amdgcn_mfma_f32_16x16x32_bf16(ax4[3], wc[3], o, 0, 0, 0);
        f32x4 a5v = {0.f, 0.f, 0.f, 0.f};
        a5v = __builtin_amdgcn_mfma_f32_16x16x32_bf16(c0, vc[0], a5v, 0, 0, 0);
        a5v = __builtin_amdgcn_mfma_f32_16x16x32_bf16(c1, vc[1], a5v, 0, 0, 0);
        const float bxv = bx[n0 + lr];
        const float b5v = b5[n0 + lr];
        #pragma unroll
        for (int r = 0; r < 4; ++r) {
            const int toff = lq * 4 + r;
            // sigmoid(a)*sigmoid(b) = 1/((1+e^-a)(1+e^-b)): one rcp
            const float ea = __expf(-(a5v[r] + b5v));
            const float eb = __expf(-(e[r] + o[r] + bxv));
            const float g = 1.0f / ((1.0f + ea) * (1.0f + eb));
            // (unsigned)v & 255 == v mod 256 (2^32 % 256 == 0)
            const int h = (int)(((unsigned)(n0 + lr + s * (tbase - toff))) & 255u);
            atomicAdd(&accum[h], g);   // per-t the h-map is a bijection
        }
        if (ntl + 1 < 16) {
            #pragma unroll
            for (int k = 0; k < 4; ++k) wc[k] = wn[k];
            vc[0] = vn[0]; vc[1] = vn[1];
        }
    }
    __syncthreads();

    // flush partial hidden (16 segment-blocks per b -> global atomic)
    atomicAdd(&out[256 + b * 256 + tid], accum[tid]);
    __threadfence();                       // release our hidden adds
    __syncthreads();

    // last block for this b computes output[b] = sigmoid(hidden . Wo + bo)
    int* flag = reinterpret_cast<int*>(accum);
    if (tid == 0) {
        const int old = atomicAdd(&cnt[b], 1);       // device-scope RMW
        __threadfence();                              // acquire
        flag[0] = (old == NSEG - 1) ? 1 : 0;
    }
    __syncthreads();
    if (!flag[0]) return;

    const float hv = __hip_atomic_load(&out[256 + b * 256 + tid],
                                       __ATOMIC_RELAXED, __HIP_MEMORY_SCOPE_AGENT);
    const float pv = hv * Wo[tid];
    __syncthreads();                       // flag read done before accum reuse
    accum[tid] = pv;
    __syncthreads();
    #pragma unroll
    for (int off = 128; off > 0; off >>= 1) {
        if (tid < off) accum[tid] += accum[tid + off];
        __syncthreads();
    }
    if (tid == 0) out[b] = sigmoid_f(accum[0] + bo[0]);
}

extern "C" void kernel_launch(void* const* d_in, const int* in_sizes, int n_in,
                              void* d_out, int out_size, void* d_ws, size_t ws_size,
                              hipStream_t stream)
{
    const float* x  = (const float*)d_in[0];
    const float* Wx = (const float*)d_in[1];
    const float* bx = (const float*)d_in[2];
    const float* W1 = (const float*)d_in[3];
    const float* b1 = (const float*)d_in[4];
    const float* W2 = (const float*)d_in[5];
    const float* b2 = (const float*)d_in[6];
    const float* W3 = (const float*)d_in[7];
    const float* b3 = (const float*)d_in[8];
    const float* W4 = (const float*)d_in[9];
    const float* b4 = (const float*)d_in[10];
    const float* W5 = (const float*)d_in[11];
    const float* b5 = (const float*)d_in[12];
    const float* Wo = (const float*)d_in[13];
    const float* bo = (const float*)d_in[14];
    const int* shiftp = (const int*)d_in[15];
    float* out = (float*)d_out;
    short* wt  = (short*)d_ws;                       // 200,704 B: bf16 fragment-ordered weights
    int* cnt   = (int*)((char*)d_ws + WT_TOTAL * 2); // 256 done-counters (1 KB)

    // prep zeroes out[] and cnt[] -> no hipMemsetAsync dispatch needed
    prep_init<<<dim3((WT_TOTAL + 255) / 256), dim3(256), 0, stream>>>(
        Wx, W1, W2, W3, W4, W5, wt, out, cnt);
    srnn_gate_scan<<<dim3(4096), dim3(256), 0, stream>>>(
        x, wt, bx, b1, b2, b3, b4, b5, shiftp, Wo, bo, cnt, out);
}